// Round 2
// baseline (10300.903 us; speedup 1.0000x reference)
//
#include <hip/hip_runtime.h>
#include <math.h>

// Problem constants: T=64, B=1024, H=512, V=512
constexpr int T_STEPS = 64;
constexpr int B_SZ = 1024;
constexpr int H_SZ = 512;
constexpr int V_SZ = 512;
constexpr int G_SZ = 4 * H_SZ; // 2048
constexpr int NBLK = 256;      // persistent grid: 1 block per CU, guaranteed resident

typedef _Float16 half8 __attribute__((ext_vector_type(8)));
typedef _Float16 half4 __attribute__((ext_vector_type(4)));
typedef float f32x4 __attribute__((ext_vector_type(4)));

__device__ __forceinline__ float4 ld4(const float* p) {
    return *reinterpret_cast<const float4*>(p);
}
__device__ __forceinline__ void st4(float* p, float4 v) {
    *reinterpret_cast<float4*>(p) = v;
}
__device__ __forceinline__ float sigf(float x) { return 1.f / (1.f + expf(-x)); }

// packed argmax word: high 32 = orderable float key, low 32 = (511 - col)
__device__ __forceinline__ unsigned long long pack_vc(float v, int col) {
    unsigned u = __float_as_uint(v);
    unsigned key = (u & 0x80000000u) ? ~u : (u | 0x80000000u);
    return ((unsigned long long)key << 32) | (unsigned)(511 - col);
}

// device-scope grid barrier (sense via monotone generation counter).
// Safe without cooperative launch: grid == 256 == #CUs and min occupancy is
// 1 block/CU, so all blocks are always co-resident.
__device__ __forceinline__ void gridbar(unsigned* cnt, unsigned* gen, unsigned target)
{
    __syncthreads();
    if (threadIdx.x == 0) {
        __threadfence(); // agent-scope release of this block's writes
        if (__hip_atomic_fetch_add(cnt, 1u, __ATOMIC_ACQ_REL, __HIP_MEMORY_SCOPE_AGENT)
            == (unsigned)(NBLK - 1)) {
            __hip_atomic_store(cnt, 0u, __ATOMIC_RELAXED, __HIP_MEMORY_SCOPE_AGENT);
            __hip_atomic_fetch_add(gen, 1u, __ATOMIC_RELEASE, __HIP_MEMORY_SCOPE_AGENT);
        } else {
            while (__hip_atomic_load(gen, __ATOMIC_ACQUIRE, __HIP_MEMORY_SCOPE_AGENT)
                   < target) {
                __builtin_amdgcn_s_sleep(1);
            }
        }
        __threadfence(); // agent-scope acquire
    }
    __syncthreads();
}

// ---------------------------------------------------------------------------
// fp32 -> (hi fp16, lo fp16) split: x ~= hi + lo/2048
// ---------------------------------------------------------------------------
__global__ __launch_bounds__(256) void cvt_pair(
    const float* __restrict__ x, _Float16* __restrict__ hi,
    _Float16* __restrict__ lo)
{
    const int i4 = blockIdx.x * 256 + threadIdx.x;
    const float4 v = ld4(x + (size_t)i4 * 4);
    half4 h, l;
    const float h0 = (float)(_Float16)v.x; h[0] = (_Float16)v.x; l[0] = (_Float16)((v.x - h0) * 2048.f);
    const float h1 = (float)(_Float16)v.y; h[1] = (_Float16)v.y; l[1] = (_Float16)((v.y - h1) * 2048.f);
    const float h2 = (float)(_Float16)v.z; h[2] = (_Float16)v.z; l[2] = (_Float16)((v.z - h2) * 2048.f);
    const float h3 = (float)(_Float16)v.w; h[3] = (_Float16)v.w; l[3] = (_Float16)((v.w - h3) * 2048.f);
    *reinterpret_cast<half4*>(hi + (size_t)i4 * 4) = h;
    *reinterpret_cast<half4*>(lo + (size_t)i4 * 4) = l;
}

// ---------------------------------------------------------------------------
// fp32 tiled NT GEMM — used once for E_gates = emb @ W_ih^T + (b_ih+b_hh)
// ---------------------------------------------------------------------------
__global__ __launch_bounds__(256) void gemm_nt_f32(
    const float* __restrict__ A, const float* __restrict__ Bw,
    float* __restrict__ C, int M, int N, int K,
    const float* __restrict__ bias1, const float* __restrict__ bias2)
{
    constexpr int BK = 16;
    __shared__ __align__(16) float As[BK][64];
    __shared__ __align__(16) float Bs[BK][64];
    const int tid = threadIdx.x;
    const int tx = tid % 16, ty = tid / 16;
    const int m0 = blockIdx.y * 64, n0 = blockIdx.x * 64;
    const int lr = tid / 4, lc = (tid % 4) * 4;
    float acc[4][4] = {};
    for (int k0 = 0; k0 < K; k0 += BK) {
        const float4 av = ld4(&A[(size_t)(m0 + lr) * K + (k0 + lc)]);
        const float4 bv = ld4(&Bw[(size_t)(n0 + lr) * K + (k0 + lc)]);
        __syncthreads();
        As[lc + 0][lr] = av.x; As[lc + 1][lr] = av.y; As[lc + 2][lr] = av.z; As[lc + 3][lr] = av.w;
        Bs[lc + 0][lr] = bv.x; Bs[lc + 1][lr] = bv.y; Bs[lc + 2][lr] = bv.z; Bs[lc + 3][lr] = bv.w;
        __syncthreads();
#pragma unroll
        for (int k = 0; k < BK; ++k) {
            const float4 a4 = ld4(&As[k][ty * 4]);
            const float4 b4 = ld4(&Bs[k][tx * 4]);
            const float ar[4] = {a4.x, a4.y, a4.z, a4.w};
            const float br[4] = {b4.x, b4.y, b4.z, b4.w};
#pragma unroll
            for (int i = 0; i < 4; ++i)
#pragma unroll
                for (int j = 0; j < 4; ++j)
                    acc[i][j] = fmaf(ar[i], br[j], acc[i][j]);
        }
    }
    const int nc = n0 + tx * 4;
    const float4 b1 = ld4(&bias1[nc]);
    const float4 b2 = ld4(&bias2[nc]);
#pragma unroll
    for (int i = 0; i < 4; ++i) {
        const int m = m0 + ty * 4 + i;
        float4 v;
        v.x = acc[i][0] + b1.x + b2.x; v.y = acc[i][1] + b1.y + b2.y;
        v.z = acc[i][2] + b1.z + b2.z; v.w = acc[i][3] + b1.w + b2.w;
        st4(&C[(size_t)m * N + nc], v);
    }
}

// ---------------------------------------------------------------------------
__global__ __launch_bounds__(256) void init_tok(
    unsigned long long* __restrict__ tok, unsigned* __restrict__ bar)
{
    const int i = blockIdx.x * 256 + threadIdx.x; // 0..2047
    tok[i] = (i < 1024) ? 511ULL : 0ULL; // buf0: token 0 (SOS); buf1: cleared
    if (i < 2) bar[i] = 0u;              // barrier {count, gen}
}

// ---------------------------------------------------------------------------
// Persistent fused decode loop. ONE launch for all 64 steps.
// Grid 256 blocks x 512 threads (8 waves = 2 waves/SIMD).
// Per step:
//   Phase A (gates GEMM + LSTM cell): block tile 64 batch x 128 gate-cols
//     (bid&15 -> h0 slice, bid>>4 -> b0). Direct global->reg streaming
//     (W_hh/h are L2-resident; no LDS staging, no K-loop barriers).
//   grid barrier
//   Phase B (logits GEMM + argmax): block tile 32 batch x 64 vocab
//     (bid&7 -> n0, bid>>3 -> m0).
//   grid barrier (except last step)
// Numerics: identical MFMA k-order to the previous 2-kernel version.
// ---------------------------------------------------------------------------
__global__ __launch_bounds__(512, 2) void decode_loop(
    const _Float16* __restrict__ Whh_hi, const _Float16* __restrict__ Whh_lo,
    const _Float16* __restrict__ Wout_hi, const _Float16* __restrict__ Wout_lo,
    const float* __restrict__ Eg, const float* __restrict__ b_out,
    _Float16* __restrict__ H0h, _Float16* __restrict__ H0l,
    _Float16* __restrict__ H1h, _Float16* __restrict__ H1l,
    float* __restrict__ cbuf, float* __restrict__ out,
    unsigned long long* __restrict__ tokbuf, unsigned* __restrict__ bar)
{
    __shared__ __align__(16) float sg[64 * 129]; // 33 KB gate-exchange buffer

    const int tid = threadIdx.x;
    const int wave = tid >> 6, lane = tid & 63;
    const int lm = lane & 15, kq = lane >> 4;
    const int bid = blockIdx.x;

    // ---- phase A invariants ----
    const int h0 = (bid & 15) * 32;
    const int b0 = (bid >> 4) * 64;
    const int wmA = wave >> 1, wnA = wave & 1;   // 4 x 2 wave grid
    const size_t aOffA = (size_t)(b0 + wmA * 16 + lm) * 512 + kq * 8;
    size_t bOffA[4];
#pragma unroll
    for (int gn = 0; gn < 4; ++gn) {
        const int c = wnA * 64 + gn * 16 + lm;             // gate-col 0..127
        const int grow = (c >> 5) * 512 + h0 + (c & 31);   // W_hh row
        bOffA[gn] = (size_t)grow * 512 + kq * 8;
    }
    // cell phase mapping: 512 thr x 4 h-cols = 64 rows x 32 cols
    const int crow = tid >> 3;
    const int hb4 = (tid & 7) * 4;
    const int bcell = b0 + crow;

    // ---- phase B invariants ----
    const int n0 = (bid & 7) * 64;
    const int m0 = (bid >> 3) * 32;
    const int wmB = wave & 1, wnB = wave >> 1;   // 2 x 4 wave grid
    const int colB = n0 + wnB * 16 + lm;
    const size_t aOffB = (size_t)(m0 + wmB * 16 + lm) * 512 + kq * 8;
    const size_t bOffB = (size_t)colB * 512 + kq * 8;

    unsigned* cnt = bar;
    unsigned* gen = bar + 1;
    unsigned target = 0;

#pragma unroll 1
    for (int t = 0; t < T_STEPS; ++t) {
        const int cur = t & 1;

        // ================= phase A: gates GEMM + cell =================
        {
            const _Float16* Ah = cur ? H1h : H0h;
            const _Float16* Al = cur ? H1l : H0l;
            _Float16* Nh = cur ? H0h : H1h;
            _Float16* Nl = cur ? H0l : H1l;

            f32x4 aH[4] = {{0.f, 0.f, 0.f, 0.f}, {0.f, 0.f, 0.f, 0.f},
                           {0.f, 0.f, 0.f, 0.f}, {0.f, 0.f, 0.f, 0.f}};
            f32x4 aC[4] = {{0.f, 0.f, 0.f, 0.f}, {0.f, 0.f, 0.f, 0.f},
                           {0.f, 0.f, 0.f, 0.f}, {0.f, 0.f, 0.f, 0.f}};
#pragma unroll
            for (int k0 = 0; k0 < 512; k0 += 32) {
                const half8 ah = *(const half8*)(Ah + aOffA + k0);
                const half8 al = *(const half8*)(Al + aOffA + k0);
                half8 bh[4], bl[4];
#pragma unroll
                for (int gn = 0; gn < 4; ++gn) {
                    bh[gn] = *(const half8*)(Whh_hi + bOffA[gn] + k0);
                    bl[gn] = *(const half8*)(Whh_lo + bOffA[gn] + k0);
                }
#pragma unroll
                for (int gn = 0; gn < 4; ++gn)
                    aH[gn] = __builtin_amdgcn_mfma_f32_16x16x32_f16(ah, bh[gn], aH[gn], 0, 0, 0);
#pragma unroll
                for (int gn = 0; gn < 4; ++gn)
                    aC[gn] = __builtin_amdgcn_mfma_f32_16x16x32_f16(ah, bl[gn], aC[gn], 0, 0, 0);
#pragma unroll
                for (int gn = 0; gn < 4; ++gn)
                    aC[gn] = __builtin_amdgcn_mfma_f32_16x16x32_f16(al, bh[gn], aC[gn], 0, 0, 0);
            }

            // gate exchange via LDS (prev step's reads are two barriers back)
            const int rw = wmA * 16 + kq * 4;
#pragma unroll
            for (int gn = 0; gn < 4; ++gn) {
                const int col = wnA * 64 + gn * 16 + lm;
#pragma unroll
                for (int r = 0; r < 4; ++r)
                    sg[(rw + r) * 129 + col] = aH[gn][r] + aC[gn][r] * (1.f / 2048.f);
            }
            __syncthreads();

            // cell math
            const unsigned long long pk = tokbuf[cur * B_SZ + bcell];
            const int tk = 511 - (int)(unsigned)(pk & 0xFFFFFFFFu);
            const float* egp = Eg + (size_t)tk * G_SZ + h0 + hb4;
            const float* sr = sg + crow * 129 + hb4;
            const float4 gI = ld4(sr);
            const float4 gF = ld4(sr + 32);
            const float4 gG = ld4(sr + 64);
            const float4 gO = ld4(sr + 96);
            const float4 eI = ld4(egp);
            const float4 eF = ld4(egp + 512);
            const float4 eG = ld4(egp + 1024);
            const float4 eO = ld4(egp + 1536);
            const size_t ci = (size_t)bcell * 512 + h0 + hb4;
            const float4 cv = ld4(cbuf + ci);

            const float iv[4] = {gI.x + eI.x, gI.y + eI.y, gI.z + eI.z, gI.w + eI.w};
            const float fv[4] = {gF.x + eF.x, gF.y + eF.y, gF.z + eF.z, gF.w + eF.w};
            const float gv[4] = {gG.x + eG.x, gG.y + eG.y, gG.z + eG.z, gG.w + eG.w};
            const float ov[4] = {gO.x + eO.x, gO.y + eO.y, gO.z + eO.z, gO.w + eO.w};
            float cc[4] = {cv.x, cv.y, cv.z, cv.w};
            float hn[4];
#pragma unroll
            for (int j = 0; j < 4; ++j) {
                const float cn = sigf(fv[j]) * cc[j] + sigf(iv[j]) * tanhf(gv[j]);
                cc[j] = cn;
                hn[j] = sigf(ov[j]) * tanhf(cn);
            }
            st4(cbuf + ci, make_float4(cc[0], cc[1], cc[2], cc[3]));
            half4 hh4, ll4;
#pragma unroll
            for (int j = 0; j < 4; ++j) {
                const _Float16 hi = (_Float16)hn[j];
                hh4[j] = hi;
                ll4[j] = (_Float16)((hn[j] - (float)hi) * 2048.f);
            }
            *reinterpret_cast<half4*>(Nh + ci) = hh4;
            *reinterpret_cast<half4*>(Nl + ci) = ll4;

            // clear next-step token slots before phase B's atomicMax
            if ((bid & 15) == 0 && tid < 64)
                tokbuf[(cur ^ 1) * B_SZ + b0 + tid] = 0ULL;
            __syncthreads(); // sg reads done before next-step writes
        }

        gridbar(cnt, gen, ++target);

        // ================= phase B: logits GEMM + argmax =================
        {
            const int nxt = (t + 1) & 1;
            const _Float16* Ah = nxt ? H1h : H0h;
            const _Float16* Al = nxt ? H1l : H0l;

            f32x4 aHb = {0.f, 0.f, 0.f, 0.f};
            f32x4 aCb = {0.f, 0.f, 0.f, 0.f};
#pragma unroll
            for (int k0 = 0; k0 < 512; k0 += 32) {
                const half8 ah = *(const half8*)(Ah + aOffB + k0);
                const half8 al = *(const half8*)(Al + aOffB + k0);
                const half8 bh = *(const half8*)(Wout_hi + bOffB + k0);
                const half8 bl = *(const half8*)(Wout_lo + bOffB + k0);
                aHb = __builtin_amdgcn_mfma_f32_16x16x32_f16(ah, bh, aHb, 0, 0, 0);
                aCb = __builtin_amdgcn_mfma_f32_16x16x32_f16(ah, bl, aCb, 0, 0, 0);
                aCb = __builtin_amdgcn_mfma_f32_16x16x32_f16(al, bh, aCb, 0, 0, 0);
            }

            const float bo = b_out[colB];
            float* outp = out + (size_t)t * B_SZ * V_SZ;
            unsigned long long best[4];
#pragma unroll
            for (int r = 0; r < 4; ++r) {
                const float v = aHb[r] + aCb[r] * (1.f / 2048.f) + bo;
                const int row = m0 + wmB * 16 + kq * 4 + r;
                outp[(size_t)row * V_SZ + colB] = v;
                best[r] = pack_vc(v, colB);
            }
#pragma unroll
            for (int r = 0; r < 4; ++r) {
#pragma unroll
                for (int off = 1; off < 16; off <<= 1) {
                    const unsigned long long o = __shfl_xor(best[r], off);
                    if (o > best[r]) best[r] = o;
                }
            }
            if (lm == 0) {
#pragma unroll
                for (int r = 0; r < 4; ++r)
                    atomicMax(&tokbuf[nxt * B_SZ + m0 + wmB * 16 + kq * 4 + r], best[r]);
            }
        }

        if (t < T_STEPS - 1) gridbar(cnt, gen, ++target);
    }
}

// ---------------------------------------------------------------------------
extern "C" void kernel_launch(void* const* d_in, const int* in_sizes, int n_in,
                              void* d_out, int out_size, void* d_ws, size_t ws_size,
                              hipStream_t stream)
{
    const float* enc_h = (const float*)d_in[2];
    const float* enc_c = (const float*)d_in[3];
    const float* emb   = (const float*)d_in[4];
    const float* W_ih  = (const float*)d_in[5];
    const float* W_hh  = (const float*)d_in[6];
    const float* b_ih  = (const float*)d_in[7];
    const float* b_hh  = (const float*)d_in[8];
    const float* W_out = (const float*)d_in[9];
    const float* b_out = (const float*)d_in[10];
    float* out = (float*)d_out;

    // workspace layout
    char* ws = (char*)d_ws;
    _Float16* Whh_hi  = (_Float16*)(ws);                          // 2 MB
    _Float16* Whh_lo  = (_Float16*)(ws + (2u << 20));             // 2 MB
    _Float16* Wout_hi = (_Float16*)(ws + (4u << 20));             // 0.5 MB
    _Float16* Wout_lo = (_Float16*)(ws + (4u << 20) + (512u << 10));
    _Float16* Hhi0 = (_Float16*)(ws + (5u << 20));
    _Float16* Hlo0 = (_Float16*)(ws + (6u << 20));
    _Float16* Hhi1 = (_Float16*)(ws + (7u << 20));
    _Float16* Hlo1 = (_Float16*)(ws + (8u << 20));
    float* cbuf = (float*)(ws + (9u << 20));                      // 2 MB
    float* Eg   = (float*)(ws + (11u << 20));                     // 4 MB
    unsigned long long* tokbuf = (unsigned long long*)(ws + (15u << 20)); // 16 KB
    unsigned* bar = (unsigned*)(ws + (15u << 20) + (16u << 10));  // 8 B

    const dim3 blk256(256);

    // one-time conversions + init
    cvt_pair<<<(G_SZ * H_SZ) / 1024, blk256, 0, stream>>>(W_hh, Whh_hi, Whh_lo);
    cvt_pair<<<(V_SZ * H_SZ) / 1024, blk256, 0, stream>>>(W_out, Wout_hi, Wout_lo);
    cvt_pair<<<(B_SZ * H_SZ) / 1024, blk256, 0, stream>>>(enc_h, Hhi0, Hlo0);
    hipMemcpyAsync(cbuf, enc_c, (size_t)B_SZ * H_SZ * 4, hipMemcpyDeviceToDevice, stream);
    init_tok<<<8, blk256, 0, stream>>>(tokbuf, bar);

    // E_gates = emb @ W_ih^T + (b_ih + b_hh)   [V x 4H], fp32, once
    gemm_nt_f32<<<dim3(G_SZ / 64, V_SZ / 64), blk256, 0, stream>>>(
        emb, W_ih, Eg, V_SZ, G_SZ, H_SZ, b_ih, b_hh);

    // fused persistent decode loop: 1 launch, 64 steps, 127 grid barriers
    decode_loop<<<NBLK, 512, 0, stream>>>(
        Whh_hi, Whh_lo, Wout_hi, Wout_lo, Eg, b_out,
        Hhi0, Hlo0, Hhi1, Hlo1, cbuf, out, tokbuf, bar);
}

// Round 3
// 3025.490 us; speedup vs baseline: 3.4047x; 3.4047x over previous
//
#include <hip/hip_runtime.h>
#include <math.h>

// Problem constants: T=64, B=1024, H=512, V=512
constexpr int T_STEPS = 64;
constexpr int B_SZ = 1024;
constexpr int H_SZ = 512;
constexpr int V_SZ = 512;
constexpr int G_SZ = 4 * H_SZ; // 2048
constexpr int NBLK = 256;      // persistent grid: 1 block per CU (128KB LDS forces it)

typedef _Float16 half8 __attribute__((ext_vector_type(8)));
typedef _Float16 half4 __attribute__((ext_vector_type(4)));
typedef float f32x4 __attribute__((ext_vector_type(4)));

__device__ __forceinline__ float4 ld4(const float* p) {
    return *reinterpret_cast<const float4*>(p);
}
__device__ __forceinline__ void st4(float* p, float4 v) {
    *reinterpret_cast<float4*>(p) = v;
}
__device__ __forceinline__ float sigf(float x) { return 1.f / (1.f + expf(-x)); }

// packed argmax word: high 32 = orderable float key, low 32 = (511 - col)
__device__ __forceinline__ unsigned long long pack_vc(float v, int col) {
    unsigned u = __float_as_uint(v);
    unsigned key = (u & 0x80000000u) ? ~u : (u | 0x80000000u);
    return ((unsigned long long)key << 32) | (unsigned)(511 - col);
}

// ---- agent-coherent (MALL-routed, sc1) accesses: relaxed atomics, NO fences,
// ---- so the per-XCD L2 is never invalidated and weights stay L2-hot.
__device__ __forceinline__ half8 ld_h8_coh(const _Float16* p) {
    const unsigned long long* q = (const unsigned long long*)p;
    union { unsigned long long u[2]; half8 h; } v;
    v.u[0] = __hip_atomic_load(q + 0, __ATOMIC_RELAXED, __HIP_MEMORY_SCOPE_AGENT);
    v.u[1] = __hip_atomic_load(q + 1, __ATOMIC_RELAXED, __HIP_MEMORY_SCOPE_AGENT);
    return v.h;
}
__device__ __forceinline__ void st_h_coh(_Float16* p, _Float16 x) {
    unsigned short u;
    __builtin_memcpy(&u, &x, 2);
    __hip_atomic_store((unsigned short*)p, u, __ATOMIC_RELAXED, __HIP_MEMORY_SCOPE_AGENT);
}
__device__ __forceinline__ float ld_f_coh(const float* p) {
    unsigned u = __hip_atomic_load((const unsigned*)p, __ATOMIC_RELAXED, __HIP_MEMORY_SCOPE_AGENT);
    return __uint_as_float(u);
}
__device__ __forceinline__ void st_f_coh(float* p, float v) {
    __hip_atomic_store((unsigned*)p, __float_as_uint(v), __ATOMIC_RELAXED, __HIP_MEMORY_SCOPE_AGENT);
}
__device__ __forceinline__ unsigned long long ld_u64_coh(const unsigned long long* p) {
    return __hip_atomic_load(p, __ATOMIC_RELAXED, __HIP_MEMORY_SCOPE_AGENT);
}
__device__ __forceinline__ void st_u64_coh(unsigned long long* p, unsigned long long v) {
    __hip_atomic_store(p, v, __ATOMIC_RELAXED, __HIP_MEMORY_SCOPE_AGENT);
}

// two-level grid barrier, monotone counters, relaxed atomics only.
// bar layout (u32): [g*32] group counters g=0..7, [256] root, [288] gen.
// Ordering: s_waitcnt vmcnt(0) guarantees this block's sc1 stores reached the
// MALL before its counter RMW; readers' post-spin sc1 loads fetch from MALL.
__device__ __forceinline__ void gridbar(unsigned* bar, unsigned target)
{
    asm volatile("s_waitcnt vmcnt(0)" ::: "memory");
    __syncthreads();
    if (threadIdx.x == 0) {
        unsigned* grp = bar + ((blockIdx.x >> 5) << 5);
        if (__hip_atomic_fetch_add(grp, 1u, __ATOMIC_RELAXED, __HIP_MEMORY_SCOPE_AGENT)
            == target * 32u - 1u) {
            if (__hip_atomic_fetch_add(bar + 256, 1u, __ATOMIC_RELAXED, __HIP_MEMORY_SCOPE_AGENT)
                == target * 8u - 1u) {
                __hip_atomic_store(bar + 288, target, __ATOMIC_RELAXED, __HIP_MEMORY_SCOPE_AGENT);
            }
        }
        while (__hip_atomic_load(bar + 288, __ATOMIC_RELAXED, __HIP_MEMORY_SCOPE_AGENT)
               < target) {
            __builtin_amdgcn_s_sleep(2);
        }
    }
    __syncthreads();
    asm volatile("" ::: "memory");
}

// ---------------------------------------------------------------------------
// fp32 -> (hi fp16, lo fp16) split: x ~= hi + lo/2048
// ---------------------------------------------------------------------------
__global__ __launch_bounds__(256) void cvt_pair(
    const float* __restrict__ x, _Float16* __restrict__ hi,
    _Float16* __restrict__ lo)
{
    const int i4 = blockIdx.x * 256 + threadIdx.x;
    const float4 v = ld4(x + (size_t)i4 * 4);
    half4 h, l;
    const float h0 = (float)(_Float16)v.x; h[0] = (_Float16)v.x; l[0] = (_Float16)((v.x - h0) * 2048.f);
    const float h1 = (float)(_Float16)v.y; h[1] = (_Float16)v.y; l[1] = (_Float16)((v.y - h1) * 2048.f);
    const float h2 = (float)(_Float16)v.z; h[2] = (_Float16)v.z; l[2] = (_Float16)((v.z - h2) * 2048.f);
    const float h3 = (float)(_Float16)v.w; h[3] = (_Float16)v.w; l[3] = (_Float16)((v.w - h3) * 2048.f);
    *reinterpret_cast<half4*>(hi + (size_t)i4 * 4) = h;
    *reinterpret_cast<half4*>(lo + (size_t)i4 * 4) = l;
}

// ---------------------------------------------------------------------------
// fp32 tiled NT GEMM — used once for E_gates = emb @ W_ih^T + (b_ih+b_hh)
// ---------------------------------------------------------------------------
__global__ __launch_bounds__(256) void gemm_nt_f32(
    const float* __restrict__ A, const float* __restrict__ Bw,
    float* __restrict__ C, int M, int N, int K,
    const float* __restrict__ bias1, const float* __restrict__ bias2)
{
    constexpr int BK = 16;
    __shared__ __align__(16) float As[BK][64];
    __shared__ __align__(16) float Bs[BK][64];
    const int tid = threadIdx.x;
    const int tx = tid % 16, ty = tid / 16;
    const int m0 = blockIdx.y * 64, n0 = blockIdx.x * 64;
    const int lr = tid / 4, lc = (tid % 4) * 4;
    float acc[4][4] = {};
    for (int k0 = 0; k0 < K; k0 += BK) {
        const float4 av = ld4(&A[(size_t)(m0 + lr) * K + (k0 + lc)]);
        const float4 bv = ld4(&Bw[(size_t)(n0 + lr) * K + (k0 + lc)]);
        __syncthreads();
        As[lc + 0][lr] = av.x; As[lc + 1][lr] = av.y; As[lc + 2][lr] = av.z; As[lc + 3][lr] = av.w;
        Bs[lc + 0][lr] = bv.x; Bs[lc + 1][lr] = bv.y; Bs[lc + 2][lr] = bv.z; Bs[lc + 3][lr] = bv.w;
        __syncthreads();
#pragma unroll
        for (int k = 0; k < BK; ++k) {
            const float4 a4 = ld4(&As[k][ty * 4]);
            const float4 b4 = ld4(&Bs[k][tx * 4]);
            const float ar[4] = {a4.x, a4.y, a4.z, a4.w};
            const float br[4] = {b4.x, b4.y, b4.z, b4.w};
#pragma unroll
            for (int i = 0; i < 4; ++i)
#pragma unroll
                for (int j = 0; j < 4; ++j)
                    acc[i][j] = fmaf(ar[i], br[j], acc[i][j]);
        }
    }
    const int nc = n0 + tx * 4;
    const float4 b1 = ld4(&bias1[nc]);
    const float4 b2 = ld4(&bias2[nc]);
#pragma unroll
    for (int i = 0; i < 4; ++i) {
        const int m = m0 + ty * 4 + i;
        float4 v;
        v.x = acc[i][0] + b1.x + b2.x; v.y = acc[i][1] + b1.y + b2.y;
        v.z = acc[i][2] + b1.z + b2.z; v.w = acc[i][3] + b1.w + b2.w;
        st4(&C[(size_t)m * N + nc], v);
    }
}

// ---------------------------------------------------------------------------
__global__ __launch_bounds__(256) void init_tok(
    unsigned long long* __restrict__ tok, unsigned* __restrict__ bar)
{
    const int i = blockIdx.x * 256 + threadIdx.x; // 0..2047
    tok[i] = (i < 1024) ? 511ULL : 0ULL; // buf0: token 0 (SOS); buf1: cleared
    if (i < 512) bar[i] = 0u;            // barrier counters
}

// ---------------------------------------------------------------------------
// Persistent fused decode loop. ONE launch for all 64 steps; NO cache fences.
// Grid 256 x 512 thr (2 waves/SIMD). Dynamic LDS 129 KB:
//   [0,64K)  W_hh hi slice (64 gate-cols x 512 halves, XOR-swizzled), resident
//   [64K,128K) W_hh lo slice
//   [128K,+1K) phase-B argmax reduce buffer
// Phase A: tile 128 batch x 64 gate-cols (= 4 gates x 16 h-cols); 8 waves each
//   own 16 batches; h via coherent 8B loads; W from LDS; cell IN REGISTERS
//   (each lane holds all 4 gates of its h-column).
// Phase B: tile 32 batch x 64 vocab; W_out L2-cached; h coherent; LDS argmax
//   reduce then 1 atomicMax per batch row.
// ---------------------------------------------------------------------------
__global__ __launch_bounds__(512, 2) void decode_loop(
    const _Float16* __restrict__ Whh_hi, const _Float16* __restrict__ Whh_lo,
    const _Float16* __restrict__ Wout_hi, const _Float16* __restrict__ Wout_lo,
    const float* __restrict__ Eg, const float* __restrict__ b_out,
    _Float16* __restrict__ H0h, _Float16* __restrict__ H0l,
    _Float16* __restrict__ H1h, _Float16* __restrict__ H1l,
    float* __restrict__ cbuf, float* __restrict__ out,
    unsigned long long* __restrict__ tokbuf, unsigned* __restrict__ bar)
{
    extern __shared__ __align__(16) char lds[];
    char* sWh = lds;                 // 64 KB
    char* sWl = lds + 65536;         // 64 KB
    unsigned long long* sbest = (unsigned long long*)(lds + 131072); // 1 KB

    const int tid = threadIdx.x;
    const int wave = tid >> 6, lane = tid & 63;
    const int lm = lane & 15, kq = lane >> 4;
    const int bid = blockIdx.x;

    // ---- phase A geometry ----
    const int hc0 = (bid & 31) * 16;   // h-column slice
    const int b0 = (bid >> 5) * 128;   // batch slice

    // ---- stage W_hh slice into LDS once (normal cached loads; read-only) ----
    // local gate-col c = gn*16 + j  <->  W_hh row (c>>4)*512 + hc0 + (c&15).
    // 16B chunk j stored at slot (j ^ (c&7)) to kill the stride-1KB bank clash.
    {
        const int c = tid >> 3;        // 0..63
        const int s0 = tid & 7;
        const int grow = (c >> 4) * 512 + hc0 + (c & 15);
        const _Float16* gh = Whh_hi + (size_t)grow * 512;
        const _Float16* gl = Whh_lo + (size_t)grow * 512;
#pragma unroll
        for (int i = 0; i < 8; ++i) {
            const int j = s0 + 8 * i;              // global 16B-chunk 0..63
            const int sw = j ^ (c & 7);
            *(half8*)(sWh + c * 1024 + sw * 16) = *(const half8*)(gh + j * 8);
            *(half8*)(sWl + c * 1024 + sw * 16) = *(const half8*)(gl + j * 8);
        }
    }
    __syncthreads();

    // A-operand (h) address: rows = batches, each wave owns 16 rows
    const size_t aOffA = (size_t)(b0 + wave * 16 + lm) * 512 + kq * 8;
    // LDS B read bases (row = gn*16+lm), XOR key = (lm&7)
    int cbase[4];
#pragma unroll
    for (int gn = 0; gn < 4; ++gn) cbase[gn] = (gn * 16 + lm) * 1024;
    const int cx = lm & 7;
    const int hc = hc0 + lm;

    // ---- phase B geometry ----
    const int n0 = (bid & 7) * 64;
    const int m0 = (bid >> 3) * 32;
    const int wmB = wave & 1, wnB = wave >> 1;
    const int colB = n0 + wnB * 16 + lm;
    const size_t aOffB = (size_t)(m0 + wmB * 16 + lm) * 512 + kq * 8;
    const size_t bOffB = (size_t)colB * 512 + kq * 8;

    unsigned target = 0;

#pragma unroll 1
    for (int t = 0; t < T_STEPS; ++t) {
        const int cur = t & 1;

        // ================= phase A: gates GEMM + register cell =================
        {
            const _Float16* Ah = cur ? H1h : H0h;
            const _Float16* Al = cur ? H1l : H0l;
            _Float16* Nh = cur ? H0h : H1h;
            _Float16* Nl = cur ? H0l : H1l;

            f32x4 aH[4] = {{0.f, 0.f, 0.f, 0.f}, {0.f, 0.f, 0.f, 0.f},
                           {0.f, 0.f, 0.f, 0.f}, {0.f, 0.f, 0.f, 0.f}};
            f32x4 aC[4] = {{0.f, 0.f, 0.f, 0.f}, {0.f, 0.f, 0.f, 0.f},
                           {0.f, 0.f, 0.f, 0.f}, {0.f, 0.f, 0.f, 0.f}};
#pragma unroll
            for (int k0 = 0; k0 < 512; k0 += 32) {
                const half8 ah = ld_h8_coh(Ah + aOffA + k0);
                const half8 al = ld_h8_coh(Al + aOffA + k0);
                const int slot = (k0 >> 3) + kq;   // 16B chunk within row
                half8 bh[4], bl[4];
#pragma unroll
                for (int gn = 0; gn < 4; ++gn) {
                    const int off = cbase[gn] + (((slot & 7) ^ cx) | (slot & ~7)) * 16;
                    bh[gn] = *(const half8*)(sWh + off);
                    bl[gn] = *(const half8*)(sWl + off);
                }
#pragma unroll
                for (int gn = 0; gn < 4; ++gn)
                    aH[gn] = __builtin_amdgcn_mfma_f32_16x16x32_f16(ah, bh[gn], aH[gn], 0, 0, 0);
#pragma unroll
                for (int gn = 0; gn < 4; ++gn)
                    aC[gn] = __builtin_amdgcn_mfma_f32_16x16x32_f16(ah, bl[gn], aC[gn], 0, 0, 0);
#pragma unroll
                for (int gn = 0; gn < 4; ++gn)
                    aC[gn] = __builtin_amdgcn_mfma_f32_16x16x32_f16(al, bh[gn], aC[gn], 0, 0, 0);
            }

            // cell: lane (lm,kq) of wave holds gates i,f,g,o (gn=0..3) for
            // batches b0+wave*16+kq*4+r, h-col hc. No LDS exchange needed.
#pragma unroll
            for (int r = 0; r < 4; ++r) {
                const int bb = b0 + wave * 16 + kq * 4 + r;
                const unsigned long long pk = ld_u64_coh(&tokbuf[cur * B_SZ + bb]);
                const int tk = 511 - (int)(unsigned)(pk & 0xFFFFFFFFu);
                const float* eg = Eg + (size_t)tk * G_SZ + hc;
                const float iv = aH[0][r] + aC[0][r] * (1.f / 2048.f) + eg[0];
                const float fv = aH[1][r] + aC[1][r] * (1.f / 2048.f) + eg[512];
                const float gv = aH[2][r] + aC[2][r] * (1.f / 2048.f) + eg[1024];
                const float ov = aH[3][r] + aC[3][r] * (1.f / 2048.f) + eg[1536];
                const size_t ci = (size_t)bb * 512 + hc;
                const float cc = ld_f_coh(cbuf + ci);
                const float cn = sigf(fv) * cc + sigf(iv) * tanhf(gv);
                const float hn = sigf(ov) * tanhf(cn);
                st_f_coh(cbuf + ci, cn);
                const _Float16 hi = (_Float16)hn;
                const _Float16 lo = (_Float16)((hn - (float)hi) * 2048.f);
                st_h_coh(Nh + ci, hi);
                st_h_coh(Nl + ci, lo);
            }

            // clear next-step token slots before phase B's atomicMax
            if ((bid & 31) == 0 && tid < 128)
                st_u64_coh(&tokbuf[(cur ^ 1) * B_SZ + b0 + tid], 0ULL);
        }

        gridbar(bar, ++target);

        // ================= phase B: logits GEMM + argmax =================
        {
            const int nxt = (t + 1) & 1;
            const _Float16* Ah = nxt ? H1h : H0h;
            const _Float16* Al = nxt ? H1l : H0l;

            f32x4 aHb = {0.f, 0.f, 0.f, 0.f};
            f32x4 aCb = {0.f, 0.f, 0.f, 0.f};
#pragma unroll
            for (int k0 = 0; k0 < 512; k0 += 32) {
                const half8 ah = ld_h8_coh(Ah + aOffB + k0);
                const half8 al = ld_h8_coh(Al + aOffB + k0);
                const half8 bh = *(const half8*)(Wout_hi + bOffB + k0);
                const half8 bl = *(const half8*)(Wout_lo + bOffB + k0);
                aHb = __builtin_amdgcn_mfma_f32_16x16x32_f16(ah, bh, aHb, 0, 0, 0);
                aCb = __builtin_amdgcn_mfma_f32_16x16x32_f16(ah, bl, aCb, 0, 0, 0);
                aCb = __builtin_amdgcn_mfma_f32_16x16x32_f16(al, bh, aCb, 0, 0, 0);
            }

            const float bo = b_out[colB];
            float* outp = out + (size_t)t * B_SZ * V_SZ;
            unsigned long long best[4];
#pragma unroll
            for (int r = 0; r < 4; ++r) {
                const float v = aHb[r] + aCb[r] * (1.f / 2048.f) + bo;
                const int row = m0 + wmB * 16 + kq * 4 + r;
                __builtin_nontemporal_store(v, &outp[(size_t)row * V_SZ + colB]);
                best[r] = pack_vc(v, colB);
            }
#pragma unroll
            for (int r = 0; r < 4; ++r) {
#pragma unroll
                for (int off = 1; off < 16; off <<= 1) {
                    const unsigned long long o = __shfl_xor(best[r], off);
                    if (o > best[r]) best[r] = o;
                }
            }
            if (lm == 0) {
#pragma unroll
                for (int r = 0; r < 4; ++r)
                    sbest[wnB * 32 + wmB * 16 + kq * 4 + r] = best[r];
            }
            __syncthreads();
            if (tid < 32) {
                unsigned long long m = sbest[tid];
                if (sbest[32 + tid] > m) m = sbest[32 + tid];
                if (sbest[64 + tid] > m) m = sbest[64 + tid];
                if (sbest[96 + tid] > m) m = sbest[96 + tid];
                atomicMax(&tokbuf[nxt * B_SZ + m0 + tid], m);
            }
        }

        if (t < T_STEPS - 1) gridbar(bar, ++target);
    }
}

// ---------------------------------------------------------------------------
extern "C" void kernel_launch(void* const* d_in, const int* in_sizes, int n_in,
                              void* d_out, int out_size, void* d_ws, size_t ws_size,
                              hipStream_t stream)
{
    const float* enc_h = (const float*)d_in[2];
    const float* enc_c = (const float*)d_in[3];
    const float* emb   = (const float*)d_in[4];
    const float* W_ih  = (const float*)d_in[5];
    const float* W_hh  = (const float*)d_in[6];
    const float* b_ih  = (const float*)d_in[7];
    const float* b_hh  = (const float*)d_in[8];
    const float* W_out = (const float*)d_in[9];
    const float* b_out = (const float*)d_in[10];
    float* out = (float*)d_out;

    // workspace layout
    char* ws = (char*)d_ws;
    _Float16* Whh_hi  = (_Float16*)(ws);                          // 2 MB
    _Float16* Whh_lo  = (_Float16*)(ws + (2u << 20));             // 2 MB
    _Float16* Wout_hi = (_Float16*)(ws + (4u << 20));             // 0.5 MB
    _Float16* Wout_lo = (_Float16*)(ws + (4u << 20) + (512u << 10));
    _Float16* Hhi0 = (_Float16*)(ws + (5u << 20));
    _Float16* Hlo0 = (_Float16*)(ws + (6u << 20));
    _Float16* Hhi1 = (_Float16*)(ws + (7u << 20));
    _Float16* Hlo1 = (_Float16*)(ws + (8u << 20));
    float* cbuf = (float*)(ws + (9u << 20));                      // 2 MB
    float* Eg   = (float*)(ws + (11u << 20));                     // 4 MB
    unsigned long long* tokbuf = (unsigned long long*)(ws + (15u << 20)); // 16 KB
    unsigned* bar = (unsigned*)(ws + (15u << 20) + (16u << 10));  // 2 KB

    const dim3 blk256(256);
    constexpr unsigned DYN_LDS = 131072 + 1024;

    static bool attr_done = false;
    if (!attr_done) {
        (void)hipFuncSetAttribute((const void*)decode_loop,
                                  hipFuncAttributeMaxDynamicSharedMemorySize,
                                  (int)DYN_LDS);
        attr_done = true;
    }

    // one-time conversions + init
    cvt_pair<<<(G_SZ * H_SZ) / 1024, blk256, 0, stream>>>(W_hh, Whh_hi, Whh_lo);
    cvt_pair<<<(V_SZ * H_SZ) / 1024, blk256, 0, stream>>>(W_out, Wout_hi, Wout_lo);
    cvt_pair<<<(B_SZ * H_SZ) / 1024, blk256, 0, stream>>>(enc_h, Hhi0, Hlo0);
    hipMemcpyAsync(cbuf, enc_c, (size_t)B_SZ * H_SZ * 4, hipMemcpyDeviceToDevice, stream);
    init_tok<<<8, blk256, 0, stream>>>(tokbuf, bar);

    // E_gates = emb @ W_ih^T + (b_ih + b_hh)   [V x 4H], fp32, once
    gemm_nt_f32<<<dim3(G_SZ / 64, V_SZ / 64), blk256, 0, stream>>>(
        emb, W_ih, Eg, V_SZ, G_SZ, H_SZ, b_ih, b_hh);

    // fused persistent decode loop: 1 launch, 64 steps, no L2 invalidation
    decode_loop<<<NBLK, 512, DYN_LDS, stream>>>(
        Whh_hi, Whh_lo, Wout_hi, Wout_lo, Eg, b_out,
        Hhi0, Hlo0, Hhi1, Hlo1, cbuf, out, tokbuf, bar);
}

// Round 5
// 2922.686 us; speedup vs baseline: 3.5245x; 1.0352x over previous
//
#include <hip/hip_runtime.h>
#include <math.h>

// Problem constants: T=64, B=1024, H=512, V=512
constexpr int T_STEPS = 64;
constexpr int B_SZ = 1024;
constexpr int H_SZ = 512;
constexpr int V_SZ = 512;
constexpr int G_SZ = 4 * H_SZ; // 2048
constexpr int NBLK = 256;      // persistent grid: 1 block per CU (128KB LDS forces it)

typedef _Float16 half8 __attribute__((ext_vector_type(8)));
typedef _Float16 half4 __attribute__((ext_vector_type(4)));
typedef float f32x4 __attribute__((ext_vector_type(4)));

__device__ __forceinline__ float4 ld4(const float* p) {
    return *reinterpret_cast<const float4*>(p);
}
__device__ __forceinline__ void st4(float* p, float4 v) {
    *reinterpret_cast<float4*>(p) = v;
}
__device__ __forceinline__ float sigf(float x) { return 1.f / (1.f + expf(-x)); }

// packed argmax word: high 32 = orderable float key, low 32 = (511 - col)
__device__ __forceinline__ unsigned long long pack_vc(float v, int col) {
    unsigned u = __float_as_uint(v);
    unsigned key = (u & 0x80000000u) ? ~u : (u | 0x80000000u);
    return ((unsigned long long)key << 32) | (unsigned)(511 - col);
}

// ---- agent-coherent (MALL-routed, sc1) accesses: relaxed atomics, NO fences,
// ---- so the per-XCD L2 is never invalidated and weights stay L2-hot.
__device__ __forceinline__ half8 ld_h8_coh(const _Float16* p) {
    const unsigned long long* q = (const unsigned long long*)p;
    union { unsigned long long u[2]; half8 h; } v;
    v.u[0] = __hip_atomic_load(q + 0, __ATOMIC_RELAXED, __HIP_MEMORY_SCOPE_AGENT);
    v.u[1] = __hip_atomic_load(q + 1, __ATOMIC_RELAXED, __HIP_MEMORY_SCOPE_AGENT);
    return v.h;
}
__device__ __forceinline__ void st_h_coh(_Float16* p, _Float16 x) {
    unsigned short u;
    __builtin_memcpy(&u, &x, 2);
    __hip_atomic_store((unsigned short*)p, u, __ATOMIC_RELAXED, __HIP_MEMORY_SCOPE_AGENT);
}
__device__ __forceinline__ unsigned long long ld_u64_coh(const unsigned long long* p) {
    return __hip_atomic_load(p, __ATOMIC_RELAXED, __HIP_MEMORY_SCOPE_AGENT);
}
__device__ __forceinline__ void st_u64_coh(unsigned long long* p, unsigned long long v) {
    __hip_atomic_store(p, v, __ATOMIC_RELAXED, __HIP_MEMORY_SCOPE_AGENT);
}

// two-level grid barrier, monotone counters, relaxed atomics only.
// bar layout (u32): [g*32] group counters g=0..7, [256] root, [288] gen.
// Ordering: s_waitcnt vmcnt(0) guarantees this block's sc1 stores reached the
// MALL before its counter RMW; readers' post-spin sc1 loads fetch from MALL.
__device__ __forceinline__ void gridbar(unsigned* bar, unsigned target)
{
    asm volatile("s_waitcnt vmcnt(0)" ::: "memory");
    __syncthreads();
    if (threadIdx.x == 0) {
        unsigned* grp = bar + ((blockIdx.x >> 5) << 5);
        if (__hip_atomic_fetch_add(grp, 1u, __ATOMIC_RELAXED, __HIP_MEMORY_SCOPE_AGENT)
            == target * 32u - 1u) {
            if (__hip_atomic_fetch_add(bar + 256, 1u, __ATOMIC_RELAXED, __HIP_MEMORY_SCOPE_AGENT)
                == target * 8u - 1u) {
                __hip_atomic_store(bar + 288, target, __ATOMIC_RELAXED, __HIP_MEMORY_SCOPE_AGENT);
            }
        }
        while (__hip_atomic_load(bar + 288, __ATOMIC_RELAXED, __HIP_MEMORY_SCOPE_AGENT)
               < target) {
            __builtin_amdgcn_s_sleep(1);
        }
    }
    __syncthreads();
    asm volatile("" ::: "memory");
}

// ---------------------------------------------------------------------------
// fp32 -> (hi fp16, lo fp16) split: x ~= hi + lo/2048
// ---------------------------------------------------------------------------
__global__ __launch_bounds__(256) void cvt_pair(
    const float* __restrict__ x, _Float16* __restrict__ hi,
    _Float16* __restrict__ lo)
{
    const int i4 = blockIdx.x * 256 + threadIdx.x;
    const float4 v = ld4(x + (size_t)i4 * 4);
    half4 h, l;
    const float h0 = (float)(_Float16)v.x; h[0] = (_Float16)v.x; l[0] = (_Float16)((v.x - h0) * 2048.f);
    const float h1 = (float)(_Float16)v.y; h[1] = (_Float16)v.y; l[1] = (_Float16)((v.y - h1) * 2048.f);
    const float h2 = (float)(_Float16)v.z; h[2] = (_Float16)v.z; l[2] = (_Float16)((v.z - h2) * 2048.f);
    const float h3 = (float)(_Float16)v.w; h[3] = (_Float16)v.w; l[3] = (_Float16)((v.w - h3) * 2048.f);
    *reinterpret_cast<half4*>(hi + (size_t)i4 * 4) = h;
    *reinterpret_cast<half4*>(lo + (size_t)i4 * 4) = l;
}

// ---------------------------------------------------------------------------
// fp32 tiled NT GEMM — used once for E_gates = emb @ W_ih^T + (b_ih+b_hh)
// ---------------------------------------------------------------------------
__global__ __launch_bounds__(256) void gemm_nt_f32(
    const float* __restrict__ A, const float* __restrict__ Bw,
    float* __restrict__ C, int M, int N, int K,
    const float* __restrict__ bias1, const float* __restrict__ bias2)
{
    constexpr int BK = 16;
    __shared__ __align__(16) float As[BK][64];
    __shared__ __align__(16) float Bs[BK][64];
    const int tid = threadIdx.x;
    const int tx = tid % 16, ty = tid / 16;
    const int m0 = blockIdx.y * 64, n0 = blockIdx.x * 64;
    const int lr = tid / 4, lc = (tid % 4) * 4;
    float acc[4][4] = {};
    for (int k0 = 0; k0 < K; k0 += BK) {
        const float4 av = ld4(&A[(size_t)(m0 + lr) * K + (k0 + lc)]);
        const float4 bv = ld4(&Bw[(size_t)(n0 + lr) * K + (k0 + lc)]);
        __syncthreads();
        As[lc + 0][lr] = av.x; As[lc + 1][lr] = av.y; As[lc + 2][lr] = av.z; As[lc + 3][lr] = av.w;
        Bs[lc + 0][lr] = bv.x; Bs[lc + 1][lr] = bv.y; Bs[lc + 2][lr] = bv.z; Bs[lc + 3][lr] = bv.w;
        __syncthreads();
#pragma unroll
        for (int k = 0; k < BK; ++k) {
            const float4 a4 = ld4(&As[k][ty * 4]);
            const float4 b4 = ld4(&Bs[k][tx * 4]);
            const float ar[4] = {a4.x, a4.y, a4.z, a4.w};
            const float br[4] = {b4.x, b4.y, b4.z, b4.w};
#pragma unroll
            for (int i = 0; i < 4; ++i)
#pragma unroll
                for (int j = 0; j < 4; ++j)
                    acc[i][j] = fmaf(ar[i], br[j], acc[i][j]);
        }
    }
    const int nc = n0 + tx * 4;
    const float4 b1 = ld4(&bias1[nc]);
    const float4 b2 = ld4(&bias2[nc]);
#pragma unroll
    for (int i = 0; i < 4; ++i) {
        const int m = m0 + ty * 4 + i;
        float4 v;
        v.x = acc[i][0] + b1.x + b2.x; v.y = acc[i][1] + b1.y + b2.y;
        v.z = acc[i][2] + b1.z + b2.z; v.w = acc[i][3] + b1.w + b2.w;
        st4(&C[(size_t)m * N + nc], v);
    }
}

// ---------------------------------------------------------------------------
__global__ __launch_bounds__(256) void init_tok(
    unsigned long long* __restrict__ tok, unsigned* __restrict__ bar)
{
    const int i = blockIdx.x * 256 + threadIdx.x; // 0..2047
    tok[i] = (i < 1024) ? 511ULL : 0ULL; // buf0: token 0 (SOS); buf1: cleared
    if (i < 512) bar[i] = 0u;            // barrier counters
}

// ---------------------------------------------------------------------------
// Persistent fused decode loop, one launch, no cache fences.
// Grid 256 x 512 thr. LDS: W_hh slice 128KB resident + 1KB argmax buffer.
// vs r3: 4-deep SW pipeline on all sc1 h loads; cross-step h prefetch issued
// before the trailing barrier; tok/Eg gathers hoisted under the GEMM; phase B
// retiled 16x128 (h dup 4x). NEW vs r4: cell state c lives in 4 VGPRs for the
// whole kernel (thread-exclusive, not an output) — zero c memory traffic and
// no cross-XCD line-sharing hazard.
// ---------------------------------------------------------------------------
__global__ __launch_bounds__(512, 2) void decode_loop(
    const _Float16* __restrict__ Whh_hi, const _Float16* __restrict__ Whh_lo,
    const _Float16* __restrict__ Wout_hi, const _Float16* __restrict__ Wout_lo,
    const float* __restrict__ Eg, const float* __restrict__ b_out,
    _Float16* __restrict__ H0h, _Float16* __restrict__ H0l,
    _Float16* __restrict__ H1h, _Float16* __restrict__ H1l,
    const float* __restrict__ cinit, float* __restrict__ out,
    unsigned long long* __restrict__ tokbuf, unsigned* __restrict__ bar)
{
    extern __shared__ __align__(16) char lds[];
    char* sWh = lds;                 // 64 KB
    char* sWl = lds + 65536;         // 64 KB
    unsigned long long* sbest = (unsigned long long*)(lds + 131072); // 1 KB

    const int tid = threadIdx.x;
    const int wave = tid >> 6, lane = tid & 63;
    const int lm = lane & 15, kq = lane >> 4;
    const int bid = blockIdx.x;

    // ---- phase A geometry ----
    const int hc0 = (bid & 31) * 16;   // h-column slice
    const int b0 = (bid >> 5) * 128;   // batch slice
    const size_t aOffA = (size_t)(b0 + wave * 16 + lm) * 512 + kq * 8;
    const int bbase = b0 + wave * 16 + kq * 4;   // cell batch base (+r)
    const int hc = hc0 + lm;

    // issue initial cross-step prefetch of h (t=0 input = H0) ASAP
    half8 pah[4], pal[4];
#pragma unroll
    for (int d = 0; d < 4; ++d) {
        pah[d] = ld_h8_coh(H0h + aOffA + d * 32);
        pal[d] = ld_h8_coh(H0l + aOffA + d * 32);
    }

    // cell state c: thread-exclusive -> registers for the entire kernel.
    // cinit (= enc_c) is read-only from here on; plain cached loads.
    float creg[4];
#pragma unroll
    for (int r = 0; r < 4; ++r)
        creg[r] = cinit[(size_t)(bbase + r) * 512 + hc];

    // ---- stage W_hh slice into LDS once (normal cached loads; read-only) ----
    // local gate-col c = gn*16 + j <-> W_hh row (c>>4)*512 + hc0 + (c&15).
    // 16B chunk j stored at slot (j ^ (c&7)).
    {
        const int c = tid >> 3;
        const int s0 = tid & 7;
        const int grow = (c >> 4) * 512 + hc0 + (c & 15);
        const _Float16* gh = Whh_hi + (size_t)grow * 512;
        const _Float16* gl = Whh_lo + (size_t)grow * 512;
#pragma unroll
        for (int i = 0; i < 8; ++i) {
            const int j = s0 + 8 * i;
            const int sw = j ^ (c & 7);
            *(half8*)(sWh + c * 1024 + sw * 16) = *(const half8*)(gh + j * 8);
            *(half8*)(sWl + c * 1024 + sw * 16) = *(const half8*)(gl + j * 8);
        }
    }
    __syncthreads();

    int cbase[4];
#pragma unroll
    for (int gn = 0; gn < 4; ++gn) cbase[gn] = (gn * 16 + lm) * 1024;
    const int cx = lm & 7;

    // ---- phase B geometry: tile 16 batches x 128 vocab ----
    const int m0 = (bid >> 2) * 16;
    const int n0v = (bid & 3) * 128;
    const int colB = n0v + wave * 16 + lm;
    const size_t aOffB = (size_t)(m0 + lm) * 512 + kq * 8;
    const size_t bOffB = (size_t)colB * 512 + kq * 8;

    unsigned target = 0;

#pragma unroll 1
    for (int t = 0; t < T_STEPS; ++t) {
        const int cur = t & 1;
        const _Float16* Ah = cur ? H1h : H0h;
        const _Float16* Al = cur ? H1l : H0l;
        _Float16* Nh = cur ? H0h : H1h;
        _Float16* Nl = cur ? H0l : H1l;

        // ================= phase A: gates GEMM + register cell =================
        {
            // tok loads: final since last barrier; resolve under the GEMM
            unsigned long long pk[4];
#pragma unroll
            for (int r = 0; r < 4; ++r)
                pk[r] = ld_u64_coh(&tokbuf[cur * B_SZ + bbase + r]);

            f32x4 aH[4] = {{0.f, 0.f, 0.f, 0.f}, {0.f, 0.f, 0.f, 0.f},
                           {0.f, 0.f, 0.f, 0.f}, {0.f, 0.f, 0.f, 0.f}};
            f32x4 aC[4] = {{0.f, 0.f, 0.f, 0.f}, {0.f, 0.f, 0.f, 0.f},
                           {0.f, 0.f, 0.f, 0.f}, {0.f, 0.f, 0.f, 0.f}};
            float egv[4][4];
#pragma unroll
            for (int it = 0; it < 16; ++it) {
                const int d = it & 3;
                const half8 ah = pah[d];
                const half8 al = pal[d];
                if (it < 12) {
                    pah[d] = ld_h8_coh(Ah + aOffA + (it + 4) * 32);
                    pal[d] = ld_h8_coh(Al + aOffA + (it + 4) * 32);
                }
                if (it == 6) {
                    // pk resolved by now; issue Eg gathers (plain, L2-cached)
#pragma unroll
                    for (int r = 0; r < 4; ++r) {
                        const int tk = 511 - (int)(unsigned)(pk[r] & 0xFFFFFFFFu);
                        const float* eg = Eg + (size_t)tk * G_SZ + hc;
                        egv[r][0] = eg[0];    egv[r][1] = eg[512];
                        egv[r][2] = eg[1024]; egv[r][3] = eg[1536];
                    }
                }
                const int slot = it * 4 + kq;
                half8 bh[4], bl[4];
#pragma unroll
                for (int gn = 0; gn < 4; ++gn) {
                    const int off = cbase[gn] + (((slot & 7) ^ cx) | (slot & ~7)) * 16;
                    bh[gn] = *(const half8*)(sWh + off);
                    bl[gn] = *(const half8*)(sWl + off);
                }
#pragma unroll
                for (int gn = 0; gn < 4; ++gn)
                    aH[gn] = __builtin_amdgcn_mfma_f32_16x16x32_f16(ah, bh[gn], aH[gn], 0, 0, 0);
#pragma unroll
                for (int gn = 0; gn < 4; ++gn)
                    aC[gn] = __builtin_amdgcn_mfma_f32_16x16x32_f16(ah, bl[gn], aC[gn], 0, 0, 0);
#pragma unroll
                for (int gn = 0; gn < 4; ++gn)
                    aC[gn] = __builtin_amdgcn_mfma_f32_16x16x32_f16(al, bh[gn], aC[gn], 0, 0, 0);
            }

            // cell: lane (lm,kq) holds gates i,f,g,o (gn=0..3) for batches
            // bbase+r, h-col hc. c stays in creg[].
#pragma unroll
            for (int r = 0; r < 4; ++r) {
                const int bb = bbase + r;
                const float iv = aH[0][r] + aC[0][r] * (1.f / 2048.f) + egv[r][0];
                const float fv = aH[1][r] + aC[1][r] * (1.f / 2048.f) + egv[r][1];
                const float gv = aH[2][r] + aC[2][r] * (1.f / 2048.f) + egv[r][2];
                const float ov = aH[3][r] + aC[3][r] * (1.f / 2048.f) + egv[r][3];
                const float cn = sigf(fv) * creg[r] + sigf(iv) * tanhf(gv);
                const float hn = sigf(ov) * tanhf(cn);
                creg[r] = cn;
                const size_t ci = (size_t)bb * 512 + hc;
                const _Float16 hi = (_Float16)hn;
                const _Float16 lo = (_Float16)((hn - (float)hi) * 2048.f);
                st_h_coh(Nh + ci, hi);
                st_h_coh(Nl + ci, lo);
            }

            // clear next-step token slots before phase B's atomicMax
            if ((bid & 31) == 0 && tid < 128)
                st_u64_coh(&tokbuf[(cur ^ 1) * B_SZ + b0 + tid], 0ULL);
        }

        gridbar(bar, ++target);

        // ================= phase B: logits GEMM + argmax =================
        {
            const int nxt = (t + 1) & 1;
            const _Float16* Bh_ = Nh;   // h just produced
            const _Float16* Bl_ = Nl;
            const float bo = b_out[colB];

            half8 qah[4], qal[4], qwh[4], qwl[4];
#pragma unroll
            for (int d = 0; d < 4; ++d) {
                qah[d] = ld_h8_coh(Bh_ + aOffB + d * 32);
                qal[d] = ld_h8_coh(Bl_ + aOffB + d * 32);
                qwh[d] = *(const half8*)(Wout_hi + bOffB + d * 32);
                qwl[d] = *(const half8*)(Wout_lo + bOffB + d * 32);
            }
            f32x4 aHb = {0.f, 0.f, 0.f, 0.f};
            f32x4 aCb = {0.f, 0.f, 0.f, 0.f};
#pragma unroll
            for (int it = 0; it < 16; ++it) {
                const int d = it & 3;
                const half8 ah = qah[d], al = qal[d];
                const half8 bh = qwh[d], bl = qwl[d];
                if (it < 12) {
                    qah[d] = ld_h8_coh(Bh_ + aOffB + (it + 4) * 32);
                    qal[d] = ld_h8_coh(Bl_ + aOffB + (it + 4) * 32);
                    qwh[d] = *(const half8*)(Wout_hi + bOffB + (it + 4) * 32);
                    qwl[d] = *(const half8*)(Wout_lo + bOffB + (it + 4) * 32);
                }
                aHb = __builtin_amdgcn_mfma_f32_16x16x32_f16(ah, bh, aHb, 0, 0, 0);
                aCb = __builtin_amdgcn_mfma_f32_16x16x32_f16(ah, bl, aCb, 0, 0, 0);
                aCb = __builtin_amdgcn_mfma_f32_16x16x32_f16(al, bh, aCb, 0, 0, 0);
            }

            float* outp = out + (size_t)t * B_SZ * V_SZ;
            unsigned long long best[4];
#pragma unroll
            for (int r = 0; r < 4; ++r) {
                const float v = aHb[r] + aCb[r] * (1.f / 2048.f) + bo;
                const int row = m0 + kq * 4 + r;
                __builtin_nontemporal_store(v, &outp[(size_t)row * V_SZ + colB]);
                best[r] = pack_vc(v, colB);
            }
#pragma unroll
            for (int r = 0; r < 4; ++r) {
#pragma unroll
                for (int off = 1; off < 16; off <<= 1) {
                    const unsigned long long o = __shfl_xor(best[r], off);
                    if (o > best[r]) best[r] = o;
                }
            }
            if (lm == 0) {
#pragma unroll
                for (int r = 0; r < 4; ++r)
                    sbest[wave * 16 + kq * 4 + r] = best[r];
            }
            __syncthreads();
            if (tid < 16) {
                unsigned long long m = sbest[tid];
#pragma unroll
                for (int w = 1; w < 8; ++w)
                    if (sbest[w * 16 + tid] > m) m = sbest[w * 16 + tid];
                atomicMax(&tokbuf[nxt * B_SZ + m0 + tid], m);
            }
        }

        if (t < T_STEPS - 1) {
            // cross-step prefetch: next phase A's h input (= Nh, final since
            // before the last barrier) — hide MALL latency under barrier spin
#pragma unroll
            for (int d = 0; d < 4; ++d) {
                pah[d] = ld_h8_coh(Nh + aOffA + d * 32);
                pal[d] = ld_h8_coh(Nl + aOffA + d * 32);
            }
            gridbar(bar, ++target);
        }
    }
}

// ---------------------------------------------------------------------------
extern "C" void kernel_launch(void* const* d_in, const int* in_sizes, int n_in,
                              void* d_out, int out_size, void* d_ws, size_t ws_size,
                              hipStream_t stream)
{
    const float* enc_h = (const float*)d_in[2];
    const float* enc_c = (const float*)d_in[3];
    const float* emb   = (const float*)d_in[4];
    const float* W_ih  = (const float*)d_in[5];
    const float* W_hh  = (const float*)d_in[6];
    const float* b_ih  = (const float*)d_in[7];
    const float* b_hh  = (const float*)d_in[8];
    const float* W_out = (const float*)d_in[9];
    const float* b_out = (const float*)d_in[10];
    float* out = (float*)d_out;

    // workspace layout
    char* ws = (char*)d_ws;
    _Float16* Whh_hi  = (_Float16*)(ws);                          // 2 MB
    _Float16* Whh_lo  = (_Float16*)(ws + (2u << 20));             // 2 MB
    _Float16* Wout_hi = (_Float16*)(ws + (4u << 20));             // 0.5 MB
    _Float16* Wout_lo = (_Float16*)(ws + (4u << 20) + (512u << 10));
    _Float16* Hhi0 = (_Float16*)(ws + (5u << 20));
    _Float16* Hlo0 = (_Float16*)(ws + (6u << 20));
    _Float16* Hhi1 = (_Float16*)(ws + (7u << 20));
    _Float16* Hlo1 = (_Float16*)(ws + (8u << 20));
    float* Eg   = (float*)(ws + (11u << 20));                     // 4 MB
    unsigned long long* tokbuf = (unsigned long long*)(ws + (15u << 20)); // 16 KB
    unsigned* bar = (unsigned*)(ws + (15u << 20) + (16u << 10));  // 2 KB

    const dim3 blk256(256);
    constexpr unsigned DYN_LDS = 131072 + 1024;

    static bool attr_done = false;
    if (!attr_done) {
        (void)hipFuncSetAttribute((const void*)decode_loop,
                                  hipFuncAttributeMaxDynamicSharedMemorySize,
                                  (int)DYN_LDS);
        attr_done = true;
    }

    // one-time conversions + init
    cvt_pair<<<(G_SZ * H_SZ) / 1024, blk256, 0, stream>>>(W_hh, Whh_hi, Whh_lo);
    cvt_pair<<<(V_SZ * H_SZ) / 1024, blk256, 0, stream>>>(W_out, Wout_hi, Wout_lo);
    cvt_pair<<<(B_SZ * H_SZ) / 1024, blk256, 0, stream>>>(enc_h, Hhi0, Hlo0);
    init_tok<<<8, blk256, 0, stream>>>(tokbuf, bar);

    // E_gates = emb @ W_ih^T + (b_ih + b_hh)   [V x 4H], fp32, once
    gemm_nt_f32<<<dim3(G_SZ / 64, V_SZ / 64), blk256, 0, stream>>>(
        emb, W_ih, Eg, V_SZ, G_SZ, H_SZ, b_ih, b_hh);

    // fused persistent decode loop: 1 launch, 64 steps, no L2 invalidation.
    // c state comes straight from enc_c (read-only inside the kernel).
    decode_loop<<<NBLK, 512, DYN_LDS, stream>>>(
        Whh_hi, Whh_lo, Wout_hi, Wout_lo, Eg, b_out,
        Hhi0, Hlo0, Hhi1, Hlo1, enc_c, out, tokbuf, bar);
}